// Round 7
// baseline (457.360 us; speedup 1.0000x reference)
//
#include <hip/hip_runtime.h>

// ---------------------------------------------------------------------------
// RCSM engine, MI355X/gfx950.  FP32 in/out.  Round 7:
//  * k_up: LDS-staged coalesced float4 epilogue (was 64 scalar 4B ops/thread)
//  * k_pass2: 32-token blocks (512 grid), write-signal fused into pass 2
//    via uniform emit flag (k_wsig eliminated, no X round-trip)
//  * k_down: 1024 blocks, kt unroll; absum merged to one dispatch
// ---------------------------------------------------------------------------

#define DR   128
#define DM   1024
#define NTOK 16384
#define NOPS 32
#define COEF (1e-5f / 32.f)

typedef __attribute__((ext_vector_type(8))) short bfrag;   // 8 x bf16 bits
typedef __attribute__((ext_vector_type(4))) float f32x4;

__device__ __forceinline__ ushort f2b_bits(float f) {
  union { float f; uint i; } c; c.f = f;
  uint x = c.i;
  return (ushort)((x + 0x7fffu + ((x >> 16) & 1u)) >> 16);   // RNE
}
__device__ __forceinline__ float qeff(float w, float s) {
  float q = rintf(w / s);
  q = fminf(1.f, fmaxf(-1.f, q));
  return q * s;
}
__device__ __forceinline__ float waveRed(float v) {
#pragma unroll
  for (int m = 32; m > 0; m >>= 1) v += __shfl_xor(v, m, 64);
  return v;
}

// ---------------- ws layout (bytes; total ~5.9 MB) -------------------------
#define OFF_SUMS    0                        // 64 f32
#define OFF_OPSSC   256                      // 32 f32
#define OFF_WDE     512                      // bf16 [128][1024]
#define OFF_WUE     (OFF_WDE + 262144)       // bf16 [1024][128]
#define OFF_WRT     (OFF_WUE + 262144)       // f32  [128(d)][32(n)]
#define OFF_OPSB    (OFF_WRT + 16384)        // bf16 [32][128(o)][128(d)]
#define OFF_WMIXA   (OFF_OPSB + 1048576)     // bf16 [128(r)][128(o)]
#define OFF_WWVB    (OFF_WMIXA + 32768)      // bf16 [128(o2)][128(d)]
#define OFF_MRS     (OFF_WWVB + 32768)       // f32  [128(d)][16(j)]
#define OFF_MWS     (OFF_MRS + 8192)         // f32  [128(d)][16(j)]
#define OFF_SB      (OFF_MWS + 8192)         // f32  [16(j)][128(r)]
#define OFF_SLOTS   (OFF_SB + 8192)          // f32  [16][128]
#define OFF_WWG     (OFF_SLOTS + 8192)       // f32  [128]
#define OFF_GAMMA   (OFF_WWG + 512)
#define OFF_BETA    (OFF_GAMMA + 512)
#define OFF_WSC     (OFF_BETA + 512)
#define OFF_RF      (OFF_WSC + 256)          // bf16 [16384][128]
#define WS_TOTAL    (OFF_RF + 4194304)

// ----------------- all abs-sum reductions in one dispatch ------------------
// grid (8, 35): y=0 W_down, y=1 W_router, y=2 W_up, y>=3 ops[y-3]
__global__ __launch_bounds__(256) void k_absum_all(
    const float* __restrict__ W_down, const float* __restrict__ W_router,
    const float* __restrict__ W_up, const float* __restrict__ ops,
    float* __restrict__ sums) {
  __shared__ float ws4[4];
  const int y = blockIdx.y;
  const float* src; int n; float* dst;
  if (y == 0)      { src = W_down;   n = 131072; dst = &sums[0]; }
  else if (y == 1) { src = W_router; n = 4096;   dst = &sums[1]; }
  else if (y == 2) { src = W_up;     n = 131072; dst = &sums[2]; }
  else { src = ops + (size_t)(y - 3) * 16384; n = 16384; dst = &sums[y]; }
  float s = 0.f;
  for (int i = blockIdx.x * 256 + threadIdx.x; i < n; i += 8 * 256)
    s += fabsf(src[i]);
  s = waveRed(s);
  int lane = threadIdx.x & 63, wv = threadIdx.x >> 6;
  if (lane == 0) ws4[wv] = s;
  __syncthreads();
  if (threadIdx.x == 0) atomicAdd(dst, ws4[0] + ws4[1] + ws4[2] + ws4[3]);
}

// --------------------------- weight build ----------------------------------
__global__ __launch_bounds__(256) void k_build(
    const float* __restrict__ W_down, const float* __restrict__ W_up,
    const float* __restrict__ W_router, const float* __restrict__ ops,
    const float* __restrict__ W_read, const float* __restrict__ W_wk,
    const float* __restrict__ W_wg, const float* __restrict__ W_wv,
    const float* __restrict__ W_mix, const float* __restrict__ slots,
    const float* __restrict__ gamma, const float* __restrict__ beta,
    const float* __restrict__ wscale, int has_wsc, const float* __restrict__ sums,
    ushort* __restrict__ WdE, ushort* __restrict__ WuE, float* __restrict__ WrT,
    ushort* __restrict__ opsB, float* __restrict__ opsScale,
    ushort* __restrict__ WmixA, ushort* __restrict__ WwvB,
    float* __restrict__ Mrs, float* __restrict__ Mws, float* __restrict__ SBw,
    float* __restrict__ slotsF, float* __restrict__ WwgF,
    float* __restrict__ gammaF, float* __restrict__ betaF, float* __restrict__ wscF) {
  int id = blockIdx.x * 256 + threadIdx.x;
  const float s_wd = fmaxf(sums[0] * (1.f / 131072.f), 1e-5f);
  const float s_wr = fmaxf(sums[1] * (1.f / 4096.f), 1e-5f);
  const float s_wu = fmaxf(sums[2] * (1.f / 131072.f), 1e-5f);

  if (id < 131072) { WdE[id] = f2b_bits(qeff(W_down[id], s_wd)); return; }
  id -= 131072;
  if (id < 131072) { WuE[id] = f2b_bits(qeff(W_up[id], s_wu)); return; }
  id -= 131072;
  if (id < 4096) {
    int d = id >> 5, n = id & 31;
    WrT[id] = qeff(W_router[n * DR + d], s_wr);
    return;
  }
  id -= 4096;
  if (id < 524288) {            // opsB[n][o][d] = ternary q (bf16 exact)
    int n = id >> 14;
    float s = fmaxf(sums[3 + n] * (1.f / 16384.f), 1e-5f);
    float q = rintf(ops[id] / s);
    q = fminf(1.f, fmaxf(-1.f, q));
    opsB[id] = f2b_bits(q);
    return;
  }
  id -= 524288;
  if (id < 32) { opsScale[id] = fmaxf(sums[3 + id] * (1.f / 16384.f), 1e-5f); return; }
  id -= 32;
  if (id < 16384) {             // WmixA[r][o]
    int r = id >> 7, o = id & 127;
    WmixA[id] = f2b_bits(W_mix[r * 256 + o]);
    return;
  }
  id -= 16384;
  if (id < 16384) { WwvB[id] = f2b_bits(W_wv[id]); return; }
  id -= 16384;
  if (id < 2048) {              // Mrs[d][j]
    int d = id >> 4, j = id & 15;
    float a = 0.f;
    for (int o = 0; o < DR; ++o) a += W_read[o * DR + d] * slots[j * DR + o];
    Mrs[id] = a;
    return;
  }
  id -= 2048;
  if (id < 2048) {              // Mws[d][j]
    int d = id >> 4, j = id & 15;
    float a = 0.f;
    for (int o = 0; o < DR; ++o) a += W_wk[o * DR + d] * slots[j * DR + o];
    Mws[id] = a;
    return;
  }
  id -= 2048;
  if (id < 2048) {              // SB[j][r]
    int j = id >> 7, r = id & 127;
    float a = 0.f;
    for (int o = 0; o < DR; ++o) a += slots[j * DR + o] * W_mix[r * 256 + 128 + o];
    SBw[id] = a;
    return;
  }
  id -= 2048;
  if (id < 2048) { slotsF[id] = slots[id]; return; }
  id -= 2048;
  if (id < 128) { WwgF[id] = W_wg[id]; return; }
  id -= 128;
  if (id < 128) { gammaF[id] = gamma[id]; return; }
  id -= 128;
  if (id < 128) { betaF[id] = beta[id]; return; }
  id -= 128;
  if (id == 0) { wscF[0] = has_wsc ? wscale[0] : 0.01f; }
}

// ------------------- down projection: MFMA bf16 GEMM -----------------------
// 1024 blocks x 256 thr; 16 tokens/block; wave w -> cols w*32..w*32+31.
__global__ __launch_bounds__(256) void k_down(const float* __restrict__ hidden,
                                              const ushort* __restrict__ WdE,
                                              float* __restrict__ X) {
  const int w = threadIdx.x >> 6, lane = threadIdx.x & 63;
  const int quad = lane >> 4, mrow = lane & 15;
  const int m0 = blockIdx.x * 16;
  const int c0 = w * 32;

  f32x4 acc[2];
  acc[0] = (f32x4){0.f, 0.f, 0.f, 0.f};
  acc[1] = (f32x4){0.f, 0.f, 0.f, 0.f};

  const float* Ap = hidden + (size_t)(m0 + mrow) * DM + quad * 8;
#pragma unroll 2
  for (int kt = 0; kt < 32; ++kt) {
    float4 a0 = *(const float4*)(Ap + kt * 32);
    float4 a1 = *(const float4*)(Ap + kt * 32 + 4);
    bfrag a;
    a[0] = (short)f2b_bits(a0.x); a[1] = (short)f2b_bits(a0.y);
    a[2] = (short)f2b_bits(a0.z); a[3] = (short)f2b_bits(a0.w);
    a[4] = (short)f2b_bits(a1.x); a[5] = (short)f2b_bits(a1.y);
    a[6] = (short)f2b_bits(a1.z); a[7] = (short)f2b_bits(a1.w);
#pragma unroll
    for (int nt = 0; nt < 2; ++nt) {
      bfrag b = *(const bfrag*)(WdE + (size_t)(c0 + nt * 16 + mrow) * DM + kt * 32 + quad * 8);
      acc[nt] = __builtin_amdgcn_mfma_f32_16x16x32_bf16(a, b, acc[nt], 0, 0, 0);
    }
  }
#pragma unroll
  for (int nt = 0; nt < 2; ++nt)
#pragma unroll
    for (int r = 0; r < 4; ++r)
      X[(size_t)(m0 + quad * 4 + r) * DR + c0 + nt * 16 + mrow] = acc[nt][r];
}

// -------------------------- fused pass kernel ------------------------------
// 512 blocks x 512 threads; 32 tokens/block.
// emit==0: X updated in-place (LN output).  emit==1: write-signal fused,
// RF (bf16) written instead of X.
__global__ __launch_bounds__(512) void k_pass2(
    float* __restrict__ X, ushort* __restrict__ RF, int emit,
    const float* __restrict__ WrT, const ushort* __restrict__ opsB,
    const float* __restrict__ opsScale, const ushort* __restrict__ WmixA,
    const float* __restrict__ Mrs, const float* __restrict__ SBw,
    const float* __restrict__ gammaF, const float* __restrict__ betaF,
    const ushort* __restrict__ WwvB, const float* __restrict__ Mws,
    const float* __restrict__ slotsF, const float* __restrict__ WwgF,
    const float* __restrict__ wscF) {
  __shared__ float  xsf[32][128];      // 16 KB
  __shared__ ushort xsb[32][136];      // 8.5 KB
  __shared__ float  lg[32][32];        // 4 KB
  __shared__ float  coefT[32][32];     // 4 KB  [n][t]
  __shared__ float  attn[32][16];      // 2 KB
  __shared__ float  at2[32][16];       // 2 KB
  __shared__ int    seli[32][2];
  __shared__ float  selw[32][2];
  __shared__ float  gp[32];

  const int tid = threadIdx.x;
  const int w = tid >> 6, lane = tid & 63;
  const int quad = lane >> 4, mrow = lane & 15;
  const int t0 = blockIdx.x * 32;

  // ---- P0: load X tile
  for (int i = tid; i < 1024; i += 512) {
    float4 v = *(const float4*)(X + (size_t)t0 * DR + i * 4);
    int t = i >> 5, c = (i & 31) * 4;
    xsf[t][c] = v.x; xsf[t][c + 1] = v.y; xsf[t][c + 2] = v.z; xsf[t][c + 3] = v.w;
    xsb[t][c] = f2b_bits(v.x); xsb[t][c + 1] = f2b_bits(v.y);
    xsb[t][c + 2] = f2b_bits(v.z); xsb[t][c + 3] = f2b_bits(v.w);
  }
  __syncthreads();

  // ---- P1: router logits + read-slot scores
  for (int p = tid; p < 1024; p += 512) {
    int t = p >> 5, n = p & 31;
    float a = 0.f;
#pragma unroll 8
    for (int d = 0; d < DR; ++d) a += xsf[t][d] * WrT[d * 32 + n];
    lg[t][n] = a;
  }
  {
    int t = tid >> 4, j = tid & 15;
    if (tid < 512) {
      float a = 0.f;
#pragma unroll 8
      for (int d = 0; d < DR; ++d) a += xsf[t][d] * Mrs[d * 16 + j];
      attn[t][j] = a * 0.088388347648318447f;
    }
  }
  __syncthreads();

  if (tid < 32) {
    float v0 = -1e30f; int i0 = 0;
#pragma unroll
    for (int n = 0; n < 32; ++n) { float v = lg[tid][n]; if (v > v0) { v0 = v; i0 = n; } }
    float v1 = -1e30f; int i1 = 0;
#pragma unroll
    for (int n = 0; n < 32; ++n)
      if (n != i0) { float v = lg[tid][n]; if (v > v1) { v1 = v; i1 = n; } }
    float e = expf(v1 - v0);
    float w0 = 1.f / (1.f + e);
    seli[tid][0] = i0; seli[tid][1] = i1;
    selw[tid][0] = w0; selw[tid][1] = e * w0;
    float m = -1e30f;
#pragma unroll
    for (int j = 0; j < 16; ++j) m = fmaxf(m, attn[tid][j]);
    float s = 0.f;
#pragma unroll
    for (int j = 0; j < 16; ++j) { float ee = expf(attn[tid][j] - m); attn[tid][j] = ee; s += ee; }
    float inv = 1.f / s;
#pragma unroll
    for (int j = 0; j < 16; ++j) attn[tid][j] *= inv;
  }
  __syncthreads();

  for (int p = tid; p < 1024; p += 512) {
    int n = p >> 5, t = p & 31;
    float cf = COEF;
    if (n == seli[t][0]) cf += selw[t][0];
    if (n == seli[t][1]) cf += selw[t][1];
    coefT[n][t] = cf * opsScale[n];
  }
  __syncthreads();

  // ---- P2: 32-op MFMA GEMM.  Wave w owns cols w*16..+15, 32 tokens (2 m).
  bfrag a[2][4];
#pragma unroll
  for (int m = 0; m < 2; ++m)
#pragma unroll
    for (int kt = 0; kt < 4; ++kt)
      a[m][kt] = *(const bfrag*)&xsb[m * 16 + mrow][kt * 32 + quad * 8];

  const ushort* Bp = opsB + (size_t)(w * 16 + mrow) * DR + quad * 8;
  bfrag bc[4], bn[4];
#pragma unroll
  for (int kt = 0; kt < 4; ++kt) bc[kt] = *(const bfrag*)(Bp + kt * 32);

  f32x4 out[2];
  out[0] = (f32x4){0.f, 0.f, 0.f, 0.f};
  out[1] = (f32x4){0.f, 0.f, 0.f, 0.f};

  for (int n = 0; n < NOPS; ++n) {
    if (n + 1 < NOPS) {
      const ushort* Bn = Bp + (size_t)(n + 1) * (DR * DR);
#pragma unroll
      for (int kt = 0; kt < 4; ++kt) bn[kt] = *(const bfrag*)(Bn + kt * 32);
    }
    f32x4 tmp[2];
    tmp[0] = (f32x4){0.f, 0.f, 0.f, 0.f};
    tmp[1] = (f32x4){0.f, 0.f, 0.f, 0.f};
#pragma unroll
    for (int kt = 0; kt < 4; ++kt)
#pragma unroll
      for (int m = 0; m < 2; ++m)
        tmp[m] = __builtin_amdgcn_mfma_f32_16x16x32_bf16(a[m][kt], bc[kt], tmp[m], 0, 0, 0);
#pragma unroll
    for (int m = 0; m < 2; ++m) {
      f32x4 cf = *(const f32x4*)&coefT[n][m * 16 + quad * 4];
      out[m] += cf * tmp[m];
    }
    if (n + 1 < NOPS) {
#pragma unroll
      for (int kt = 0; kt < 4; ++kt) bc[kt] = bn[kt];
    }
  }
  __syncthreads();

  // ---- P3: AO -> xsb (bf16)
#pragma unroll
  for (int m = 0; m < 2; ++m)
#pragma unroll
    for (int r = 0; r < 4; ++r)
      xsb[m * 16 + quad * 4 + r][w * 16 + mrow] = f2b_bits(out[m][r]);
  __syncthreads();

  // ---- P4 (waves 0-1): mix GEMM + residual + mem term + LN
  if (w < 2) {
    bfrag a2[4];
#pragma unroll
    for (int kt = 0; kt < 4; ++kt)
      a2[kt] = *(const bfrag*)&xsb[w * 16 + mrow][kt * 32 + quad * 8];

    f32x4 acc[8];
#pragma unroll
    for (int i = 0; i < 8; ++i) acc[i] = (f32x4){0.f, 0.f, 0.f, 0.f};
#pragma unroll
    for (int kt = 0; kt < 4; ++kt)
#pragma unroll
      for (int nt = 0; nt < 8; ++nt) {
        bfrag b = *(const bfrag*)(WmixA + (size_t)(nt * 16 + mrow) * DR + kt * 32 + quad * 8);
        acc[nt] = __builtin_amdgcn_mfma_f32_16x16x32_bf16(a2[kt], b, acc[nt], 0, 0, 0);
      }

    float v[8][4];
#pragma unroll
    for (int nt = 0; nt < 8; ++nt) {
      const int col = nt * 16 + mrow;
#pragma unroll
      for (int r = 0; r < 4; ++r) {
        const int t = w * 16 + quad * 4 + r;
        float y0 = 0.f;
#pragma unroll
        for (int j = 0; j < 16; ++j) y0 += attn[t][j] * SBw[j * 128 + col];
        v[nt][r] = acc[nt][r] + xsf[t][col] + y0;
      }
    }
    float s[4], q[4];
#pragma unroll
    for (int r = 0; r < 4; ++r) {
      float ps = 0.f, pq = 0.f;
#pragma unroll
      for (int nt = 0; nt < 8; ++nt) { ps += v[nt][r]; pq += v[nt][r] * v[nt][r]; }
      s[r] = ps; q[r] = pq;
    }
#pragma unroll
    for (int m = 1; m < 16; m <<= 1)
#pragma unroll
      for (int r = 0; r < 4; ++r) {
        s[r] += __shfl_xor(s[r], m, 64);
        q[r] += __shfl_xor(q[r], m, 64);
      }
    float mu[4], rsd[4];
#pragma unroll
    for (int r = 0; r < 4; ++r) {
      mu[r] = s[r] * (1.f / DR);
      float var = q[r] * (1.f / DR) - mu[r] * mu[r];
      rsd[r] = rsqrtf(var + 1e-5f);
    }
    if (!emit) {
#pragma unroll
      for (int nt = 0; nt < 8; ++nt) {
        const int col = nt * 16 + mrow;
        const float g = gammaF[col], bb = betaF[col];
#pragma unroll
        for (int r = 0; r < 4; ++r) {
          const int t = w * 16 + quad * 4 + r;
          X[(size_t)(t0 + t) * DR + col] = (v[nt][r] - mu[r]) * rsd[r] * g + bb;
        }
      }
    } else {
#pragma unroll
      for (int nt = 0; nt < 8; ++nt) {
        const int col = nt * 16 + mrow;
        const float g = gammaF[col], bb = betaF[col];
#pragma unroll
        for (int r = 0; r < 4; ++r) {
          const int t = w * 16 + quad * 4 + r;
          float val = (v[nt][r] - mu[r]) * rsd[r] * g + bb;
          xsf[t][col] = val;
          xsb[t][col] = f2b_bits(val);
        }
      }
    }
  }
  if (!emit) return;

  // ================= fused write signal (pass 2 only) ======================
  __syncthreads();   // xsf/xsb now hold final reason

  // write-attention scores + gate
  {
    int t = tid >> 4, j = tid & 15;
    float a = 0.f;
#pragma unroll 8
    for (int d = 0; d < DR; ++d) a += xsf[t][d] * Mws[d * 16 + j];
    at2[t][j] = a * 0.088388347648318447f;
  }
  __syncthreads();

  if (tid < 32) {
    float z = 0.f;
#pragma unroll 8
    for (int d = 0; d < DR; ++d) z += xsf[tid][d] * WwgF[d];
    gp[tid] = wscF[0] / (1.f + expf(-z));
    float m = -1e30f;
#pragma unroll
    for (int j = 0; j < 16; ++j) m = fmaxf(m, at2[tid][j]);
    float s = 0.f;
#pragma unroll
    for (int j = 0; j < 16; ++j) { float e = expf(at2[tid][j] - m); at2[tid][j] = e; s += e; }
    float inv = 1.f / s;
#pragma unroll
    for (int j = 0; j < 16; ++j) at2[tid][j] *= inv;
  }
  __syncthreads();

  // wv GEMM + combine -> RF.  Waves 0-3: mtile = w&1, col half = (w>>1)*64.
  if (w < 4) {
    const int mtile = w & 1;
    const int ch = (w >> 1) * 64;
    bfrag a2[4];
#pragma unroll
    for (int kt = 0; kt < 4; ++kt)
      a2[kt] = *(const bfrag*)&xsb[mtile * 16 + mrow][kt * 32 + quad * 8];

    f32x4 acc[4];
#pragma unroll
    for (int i = 0; i < 4; ++i) acc[i] = (f32x4){0.f, 0.f, 0.f, 0.f};
#pragma unroll
    for (int kt = 0; kt < 4; ++kt)
#pragma unroll
      for (int nt = 0; nt < 4; ++nt) {
        bfrag b = *(const bfrag*)(WwvB + (size_t)(ch + nt * 16 + mrow) * DR + kt * 32 + quad * 8);
        acc[nt] = __builtin_amdgcn_mfma_f32_16x16x32_bf16(a2[kt], b, acc[nt], 0, 0, 0);
      }

    const float c01 = wscF[0] * 0.1f;
#pragma unroll
    for (int nt = 0; nt < 4; ++nt) {
      const int col = ch + nt * 16 + mrow;
#pragma unroll
      for (int r = 0; r < 4; ++r) {
        const int t = mtile * 16 + quad * 4 + r;
        float mo = 0.f;
#pragma unroll
        for (int j = 0; j < 16; ++j) mo += at2[t][j] * slotsF[j * DR + col];
        float val = xsf[t][col] + gp[t] * acc[nt][r] + c01 * mo;
        RF[(size_t)(t0 + t) * DR + col] = f2b_bits(val);
      }
    }
  }
}

// ---------- up projection + residual, LDS-staged coalesced epilogue --------
__global__ __launch_bounds__(256) void k_up(const ushort* __restrict__ Rf,
                                            const ushort* __restrict__ WuE,
                                            const float* __restrict__ hidden,
                                            float* __restrict__ out) {
  __shared__ float cs[64][132];   // 33.8 KB

  const int wave = threadIdx.x >> 6, lane = threadIdx.x & 63;
  const int quad = lane >> 4, mrow = lane & 15;
  const int mt = blockIdx.x >> 3, ngrp = blockIdx.x & 7;
  const int m0b = mt * 64;
  const int m0 = m0b + wave * 16;
  const int c0 = ngrp * 128;

  f32x4 acc[8];
#pragma unroll
  for (int i = 0; i < 8; ++i) acc[i] = (f32x4){0.f, 0.f, 0.f, 0.f};

  const ushort* Ap = Rf + (size_t)(m0 + mrow) * DR + quad * 8;
#pragma unroll
  for (int kt = 0; kt < 4; ++kt) {
    bfrag a = *(const bfrag*)(Ap + kt * 32);
#pragma unroll
    for (int nt = 0; nt < 8; ++nt) {
      const ushort* Bp = WuE + (size_t)(c0 + nt * 16 + mrow) * DR + kt * 32 + quad * 8;
      bfrag b = *(const bfrag*)Bp;
      acc[nt] = __builtin_amdgcn_mfma_f32_16x16x32_bf16(a, b, acc[nt], 0, 0, 0);
    }
  }
  // stage C tile in LDS
#pragma unroll
  for (int nt = 0; nt < 8; ++nt)
#pragma unroll
    for (int r = 0; r < 4; ++r)
      cs[wave * 16 + quad * 4 + r][nt * 16 + mrow] = acc[nt][r];
  __syncthreads();

  // coalesced epilogue: 8 float4 per thread
#pragma unroll
  for (int k = 0; k < 8; ++k) {
    const int i = threadIdx.x + k * 256;
    const int t = i >> 5, c4 = (i & 31) * 4;
    const size_t idx = (size_t)(m0b + t) * DM + c0 + c4;
    float4 h = *(const float4*)(hidden + idx);
    float4 v;
    v.x = h.x + cs[t][c4];
    v.y = h.y + cs[t][c4 + 1];
    v.z = h.z + cs[t][c4 + 2];
    v.w = h.w + cs[t][c4 + 3];
    *(float4*)(out + idx) = v;
  }
}

// ---------------------------------------------------------------------------
extern "C" void kernel_launch(void* const* d_in, const int* in_sizes, int n_in,
                              void* d_out, int out_size, void* d_ws, size_t ws_size,
                              hipStream_t stream) {
  int ns[20]; int nn = 0; int lastsc = -1;
  for (int i = 0; i < n_in; ++i) {
    if (in_sizes[i] == 1) lastsc = i;
    else if (nn < 20) ns[nn++] = i;
  }
  int iH = 0, iWd = 2, iWu = 3, iOps = 4, iWr = 5, iSl = 6, iRe = 7,
      iWk = 8, iWg = 9, iWv = 10, iMx = 11, iG = 12, iB = 13;
  if (nn >= 13) {
    iH  = ns[0];  iWd = ns[1];  iWu = ns[2];  iOps = ns[3]; iWr = ns[4];
    iSl = ns[5];  iRe = ns[6];  iWk = ns[7];  iWg = ns[8];  iWv = ns[9];
    iMx = ns[10]; iG  = ns[11]; iB  = ns[12];
  }
  const float* hidden   = (const float*)d_in[iH];
  const float* W_down   = (const float*)d_in[iWd];
  const float* W_up     = (const float*)d_in[iWu];
  const float* opsw     = (const float*)d_in[iOps];
  const float* W_router = (const float*)d_in[iWr];
  const float* slots    = (const float*)d_in[iSl];
  const float* W_read   = (const float*)d_in[iRe];
  const float* W_wk     = (const float*)d_in[iWk];
  const float* W_wg     = (const float*)d_in[iWg];
  const float* W_wv     = (const float*)d_in[iWv];
  const float* W_mix    = (const float*)d_in[iMx];
  const float* lng      = (const float*)d_in[iG];
  const float* lnb      = (const float*)d_in[iB];
  const float* wscale   = (lastsc >= 0) ? (const float*)d_in[lastsc] : (const float*)d_in[iG];
  const int has_wsc     = (lastsc >= 0) ? 1 : 0;

  char* ws = (char*)d_ws;
  float*  sums   = (float*)(ws + OFF_SUMS);
  float*  opsSc  = (float*)(ws + OFF_OPSSC);
  ushort* WdE    = (ushort*)(ws + OFF_WDE);
  ushort* WuE    = (ushort*)(ws + OFF_WUE);
  float*  WrT    = (float*)(ws + OFF_WRT);
  ushort* opsB   = (ushort*)(ws + OFF_OPSB);
  ushort* WmixA  = (ushort*)(ws + OFF_WMIXA);
  ushort* WwvB   = (ushort*)(ws + OFF_WWVB);
  float*  Mrs    = (float*)(ws + OFF_MRS);
  float*  Mws    = (float*)(ws + OFF_MWS);
  float*  SBw    = (float*)(ws + OFF_SB);
  float*  slotsF = (float*)(ws + OFF_SLOTS);
  float*  WwgF   = (float*)(ws + OFF_WWG);
  float*  gammaF = (float*)(ws + OFF_GAMMA);
  float*  betaF  = (float*)(ws + OFF_BETA);
  float*  wscF   = (float*)(ws + OFF_WSC);
  ushort* RF     = (ushort*)(ws + OFF_RF);

  float* X = (float*)d_out;   // staged in d_out; k_up overwrites all of d_out

  hipMemsetAsync(ws + OFF_SUMS, 0, 256, stream);
  k_absum_all<<<dim3(8, 35), 256, 0, stream>>>(W_down, W_router, W_up, opsw, sums);
  k_build<<<3250, 256, 0, stream>>>(W_down, W_up, W_router, opsw, W_read, W_wk, W_wg,
                                    W_wv, W_mix, slots, lng, lnb, wscale, has_wsc,
                                    sums, WdE, WuE, WrT, opsB, opsSc, WmixA, WwvB,
                                    Mrs, Mws, SBw, slotsF, WwgF, gammaF, betaF, wscF);
  k_down<<<1024, 256, 0, stream>>>(hidden, WdE, X);
  k_pass2<<<512, 512, 0, stream>>>(X, RF, 0, WrT, opsB, opsSc, WmixA, Mrs, SBw,
                                   gammaF, betaF, WwvB, Mws, slotsF, WwgF, wscF);
  k_pass2<<<512, 512, 0, stream>>>(X, RF, 1, WrT, opsB, opsSc, WmixA, Mrs, SBw,
                                   gammaF, betaF, WwvB, Mws, slotsF, WwgF, wscF);
  k_up<<<2048, 256, 0, stream>>>(RF, WuE, hidden, X);
}

// Round 8
// 385.093 us; speedup vs baseline: 1.1877x; 1.1877x over previous
//
#include <hip/hip_runtime.h>

// ---------------------------------------------------------------------------
// RCSM engine, MI355X/gfx950.  FP32 in/out.  Round 8:
//  * k_pass2: 64-token blocks (256 grid) restoring round-6 opsB reuse,
//    fused write-signal kept, 8-wave P4/wsig (cross-wave LN via LDS partials),
//    padded lg/attn to kill 32-way/4-way LDS bank conflicts.
//  * k_up: LDS-staged coalesced float4 epilogue (round 7, kept).
// ---------------------------------------------------------------------------

#define DR   128
#define DM   1024
#define NTOK 16384
#define NOPS 32
#define COEF (1e-5f / 32.f)

typedef __attribute__((ext_vector_type(8))) short bfrag;   // 8 x bf16 bits
typedef __attribute__((ext_vector_type(4))) float f32x4;

__device__ __forceinline__ ushort f2b_bits(float f) {
  union { float f; uint i; } c; c.f = f;
  uint x = c.i;
  return (ushort)((x + 0x7fffu + ((x >> 16) & 1u)) >> 16);   // RNE
}
__device__ __forceinline__ float qeff(float w, float s) {
  float q = rintf(w / s);
  q = fminf(1.f, fmaxf(-1.f, q));
  return q * s;
}
__device__ __forceinline__ float waveRed(float v) {
#pragma unroll
  for (int m = 32; m > 0; m >>= 1) v += __shfl_xor(v, m, 64);
  return v;
}

// ---------------- ws layout (bytes; total ~5.9 MB) -------------------------
#define OFF_SUMS    0
#define OFF_OPSSC   256
#define OFF_WDE     512
#define OFF_WUE     (OFF_WDE + 262144)
#define OFF_WRT     (OFF_WUE + 262144)
#define OFF_OPSB    (OFF_WRT + 16384)
#define OFF_WMIXA   (OFF_OPSB + 1048576)
#define OFF_WWVB    (OFF_WMIXA + 32768)
#define OFF_MRS     (OFF_WWVB + 32768)
#define OFF_MWS     (OFF_MRS + 8192)
#define OFF_SB      (OFF_MWS + 8192)
#define OFF_SLOTS   (OFF_SB + 8192)
#define OFF_WWG     (OFF_SLOTS + 8192)
#define OFF_GAMMA   (OFF_WWG + 512)
#define OFF_BETA    (OFF_GAMMA + 512)
#define OFF_WSC     (OFF_BETA + 512)
#define OFF_RF      (OFF_WSC + 256)
#define WS_TOTAL    (OFF_RF + 4194304)

// ----------------- all abs-sum reductions in one dispatch ------------------
__global__ __launch_bounds__(256) void k_absum_all(
    const float* __restrict__ W_down, const float* __restrict__ W_router,
    const float* __restrict__ W_up, const float* __restrict__ ops,
    float* __restrict__ sums) {
  __shared__ float ws4[4];
  const int y = blockIdx.y;
  const float* src; int n; float* dst;
  if (y == 0)      { src = W_down;   n = 131072; dst = &sums[0]; }
  else if (y == 1) { src = W_router; n = 4096;   dst = &sums[1]; }
  else if (y == 2) { src = W_up;     n = 131072; dst = &sums[2]; }
  else { src = ops + (size_t)(y - 3) * 16384; n = 16384; dst = &sums[y]; }
  float s = 0.f;
  for (int i = blockIdx.x * 256 + threadIdx.x; i < n; i += 8 * 256)
    s += fabsf(src[i]);
  s = waveRed(s);
  int lane = threadIdx.x & 63, wv = threadIdx.x >> 6;
  if (lane == 0) ws4[wv] = s;
  __syncthreads();
  if (threadIdx.x == 0) atomicAdd(dst, ws4[0] + ws4[1] + ws4[2] + ws4[3]);
}

// --------------------------- weight build ----------------------------------
__global__ __launch_bounds__(256) void k_build(
    const float* __restrict__ W_down, const float* __restrict__ W_up,
    const float* __restrict__ W_router, const float* __restrict__ ops,
    const float* __restrict__ W_read, const float* __restrict__ W_wk,
    const float* __restrict__ W_wg, const float* __restrict__ W_wv,
    const float* __restrict__ W_mix, const float* __restrict__ slots,
    const float* __restrict__ gamma, const float* __restrict__ beta,
    const float* __restrict__ wscale, int has_wsc, const float* __restrict__ sums,
    ushort* __restrict__ WdE, ushort* __restrict__ WuE, float* __restrict__ WrT,
    ushort* __restrict__ opsB, float* __restrict__ opsScale,
    ushort* __restrict__ WmixA, ushort* __restrict__ WwvB,
    float* __restrict__ Mrs, float* __restrict__ Mws, float* __restrict__ SBw,
    float* __restrict__ slotsF, float* __restrict__ WwgF,
    float* __restrict__ gammaF, float* __restrict__ betaF, float* __restrict__ wscF) {
  int id = blockIdx.x * 256 + threadIdx.x;
  const float s_wd = fmaxf(sums[0] * (1.f / 131072.f), 1e-5f);
  const float s_wr = fmaxf(sums[1] * (1.f / 4096.f), 1e-5f);
  const float s_wu = fmaxf(sums[2] * (1.f / 131072.f), 1e-5f);

  if (id < 131072) { WdE[id] = f2b_bits(qeff(W_down[id], s_wd)); return; }
  id -= 131072;
  if (id < 131072) { WuE[id] = f2b_bits(qeff(W_up[id], s_wu)); return; }
  id -= 131072;
  if (id < 4096) {
    int d = id >> 5, n = id & 31;
    WrT[id] = qeff(W_router[n * DR + d], s_wr);
    return;
  }
  id -= 4096;
  if (id < 524288) {
    int n = id >> 14;
    float s = fmaxf(sums[3 + n] * (1.f / 16384.f), 1e-5f);
    float q = rintf(ops[id] / s);
    q = fminf(1.f, fmaxf(-1.f, q));
    opsB[id] = f2b_bits(q);
    return;
  }
  id -= 524288;
  if (id < 32) { opsScale[id] = fmaxf(sums[3 + id] * (1.f / 16384.f), 1e-5f); return; }
  id -= 32;
  if (id < 16384) {
    int r = id >> 7, o = id & 127;
    WmixA[id] = f2b_bits(W_mix[r * 256 + o]);
    return;
  }
  id -= 16384;
  if (id < 16384) { WwvB[id] = f2b_bits(W_wv[id]); return; }
  id -= 16384;
  if (id < 2048) {
    int d = id >> 4, j = id & 15;
    float a = 0.f;
    for (int o = 0; o < DR; ++o) a += W_read[o * DR + d] * slots[j * DR + o];
    Mrs[id] = a;
    return;
  }
  id -= 2048;
  if (id < 2048) {
    int d = id >> 4, j = id & 15;
    float a = 0.f;
    for (int o = 0; o < DR; ++o) a += W_wk[o * DR + d] * slots[j * DR + o];
    Mws[id] = a;
    return;
  }
  id -= 2048;
  if (id < 2048) {
    int j = id >> 7, r = id & 127;
    float a = 0.f;
    for (int o = 0; o < DR; ++o) a += slots[j * DR + o] * W_mix[r * 256 + 128 + o];
    SBw[id] = a;
    return;
  }
  id -= 2048;
  if (id < 2048) { slotsF[id] = slots[id]; return; }
  id -= 2048;
  if (id < 128) { WwgF[id] = W_wg[id]; return; }
  id -= 128;
  if (id < 128) { gammaF[id] = gamma[id]; return; }
  id -= 128;
  if (id < 128) { betaF[id] = beta[id]; return; }
  id -= 128;
  if (id == 0) { wscF[0] = has_wsc ? wscale[0] : 0.01f; }
}

// ------------------- down projection: MFMA bf16 GEMM -----------------------
__global__ __launch_bounds__(256) void k_down(const float* __restrict__ hidden,
                                              const ushort* __restrict__ WdE,
                                              float* __restrict__ X) {
  const int w = threadIdx.x >> 6, lane = threadIdx.x & 63;
  const int quad = lane >> 4, mrow = lane & 15;
  const int m0 = blockIdx.x * 16;
  const int c0 = w * 32;

  f32x4 acc[2];
  acc[0] = (f32x4){0.f, 0.f, 0.f, 0.f};
  acc[1] = (f32x4){0.f, 0.f, 0.f, 0.f};

  const float* Ap = hidden + (size_t)(m0 + mrow) * DM + quad * 8;
#pragma unroll 2
  for (int kt = 0; kt < 32; ++kt) {
    float4 a0 = *(const float4*)(Ap + kt * 32);
    float4 a1 = *(const float4*)(Ap + kt * 32 + 4);
    bfrag a;
    a[0] = (short)f2b_bits(a0.x); a[1] = (short)f2b_bits(a0.y);
    a[2] = (short)f2b_bits(a0.z); a[3] = (short)f2b_bits(a0.w);
    a[4] = (short)f2b_bits(a1.x); a[5] = (short)f2b_bits(a1.y);
    a[6] = (short)f2b_bits(a1.z); a[7] = (short)f2b_bits(a1.w);
#pragma unroll
    for (int nt = 0; nt < 2; ++nt) {
      bfrag b = *(const bfrag*)(WdE + (size_t)(c0 + nt * 16 + mrow) * DM + kt * 32 + quad * 8);
      acc[nt] = __builtin_amdgcn_mfma_f32_16x16x32_bf16(a, b, acc[nt], 0, 0, 0);
    }
  }
#pragma unroll
  for (int nt = 0; nt < 2; ++nt)
#pragma unroll
    for (int r = 0; r < 4; ++r)
      X[(size_t)(m0 + quad * 4 + r) * DR + c0 + nt * 16 + mrow] = acc[nt][r];
}

// -------------------------- fused pass kernel ------------------------------
// 256 blocks x 512 threads; 64 tokens/block.
// emit==0: X updated in-place.  emit==1: write-signal fused, RF written.
__global__ __launch_bounds__(512) void k_pass2(
    float* __restrict__ X, ushort* __restrict__ RF, int emit,
    const float* __restrict__ WrT, const ushort* __restrict__ opsB,
    const float* __restrict__ opsScale, const ushort* __restrict__ WmixA,
    const float* __restrict__ Mrs, const float* __restrict__ SBw,
    const float* __restrict__ gammaF, const float* __restrict__ betaF,
    const ushort* __restrict__ WwvB, const float* __restrict__ Mws,
    const float* __restrict__ slotsF, const float* __restrict__ WwgF,
    const float* __restrict__ wscF) {
  __shared__ float  xsf[64][128];      // 32 KB
  __shared__ ushort xsb[64][136];      // 17 KB
  __shared__ float  lg[64][33];        // 8.4 KB (padded: top-2 reads conflict-free)
  __shared__ float  coefT[32][64];     // 8 KB
  __shared__ float  attn[64][17];      // 4.3 KB (padded)
  __shared__ float  at2[64][17];       // 4.3 KB
  __shared__ int    seli[64][2];
  __shared__ float  selw[64][2];
  __shared__ float  gp[64];
  __shared__ float  partS[8][4][4];    // cross-wave LN partials
  __shared__ float  partQ[8][4][4];

  const int tid = threadIdx.x;
  const int w = tid >> 6, lane = tid & 63;
  const int quad = lane >> 4, mrow = lane & 15;
  const int t0 = blockIdx.x * 64;

  // ---- P0: load X tile -> fp32 + bf16 LDS copies
  for (int i = tid; i < 2048; i += 512) {
    float4 v = *(const float4*)(X + (size_t)t0 * DR + i * 4);
    int t = i >> 5, c = (i & 31) * 4;
    xsf[t][c] = v.x; xsf[t][c + 1] = v.y; xsf[t][c + 2] = v.z; xsf[t][c + 3] = v.w;
    xsb[t][c] = f2b_bits(v.x); xsb[t][c + 1] = f2b_bits(v.y);
    xsb[t][c + 2] = f2b_bits(v.z); xsb[t][c + 3] = f2b_bits(v.w);
  }
  __syncthreads();

  // ---- P1: router logits + read-slot scores
  for (int p = tid; p < 2048; p += 512) {
    int t = p >> 5, n = p & 31;
    float a = 0.f;
#pragma unroll 8
    for (int d = 0; d < DR; ++d) a += xsf[t][d] * WrT[d * 32 + n];
    lg[t][n] = a;
  }
  for (int p = tid; p < 1024; p += 512) {
    int t = p >> 4, j = p & 15;
    float a = 0.f;
#pragma unroll 8
    for (int d = 0; d < DR; ++d) a += xsf[t][d] * Mrs[d * 16 + j];
    attn[t][j] = a * 0.088388347648318447f;
  }
  __syncthreads();

  if (tid < 64) {
    float v0 = -1e30f; int i0 = 0;
#pragma unroll
    for (int n = 0; n < 32; ++n) { float v = lg[tid][n]; if (v > v0) { v0 = v; i0 = n; } }
    float v1 = -1e30f; int i1 = 0;
#pragma unroll
    for (int n = 0; n < 32; ++n)
      if (n != i0) { float v = lg[tid][n]; if (v > v1) { v1 = v; i1 = n; } }
    float e = expf(v1 - v0);
    float w0 = 1.f / (1.f + e);
    seli[tid][0] = i0; seli[tid][1] = i1;
    selw[tid][0] = w0; selw[tid][1] = e * w0;
    float m = -1e30f;
#pragma unroll
    for (int j = 0; j < 16; ++j) m = fmaxf(m, attn[tid][j]);
    float s = 0.f;
#pragma unroll
    for (int j = 0; j < 16; ++j) { float ee = expf(attn[tid][j] - m); attn[tid][j] = ee; s += ee; }
    float inv = 1.f / s;
#pragma unroll
    for (int j = 0; j < 16; ++j) attn[tid][j] *= inv;
  }
  __syncthreads();

  for (int p = tid; p < 2048; p += 512) {
    int n = p >> 6, t = p & 63;
    float cf = COEF;
    if (n == seli[t][0]) cf += selw[t][0];
    if (n == seli[t][1]) cf += selw[t][1];
    coefT[n][t] = cf * opsScale[n];
  }
  __syncthreads();

  // ---- P2: 32-op MFMA GEMM.  Wave w owns cols w*16..+15, all 4 m-tiles.
  bfrag a[4][4];
#pragma unroll
  for (int m = 0; m < 4; ++m)
#pragma unroll
    for (int kt = 0; kt < 4; ++kt)
      a[m][kt] = *(const bfrag*)&xsb[m * 16 + mrow][kt * 32 + quad * 8];

  const ushort* Bp = opsB + (size_t)(w * 16 + mrow) * DR + quad * 8;
  bfrag bc[4], bn[4];
#pragma unroll
  for (int kt = 0; kt < 4; ++kt) bc[kt] = *(const bfrag*)(Bp + kt * 32);

  f32x4 out[4];
#pragma unroll
  for (int m = 0; m < 4; ++m) out[m] = (f32x4){0.f, 0.f, 0.f, 0.f};

  for (int n = 0; n < NOPS; ++n) {
    if (n + 1 < NOPS) {
      const ushort* Bn = Bp + (size_t)(n + 1) * (DR * DR);
#pragma unroll
      for (int kt = 0; kt < 4; ++kt) bn[kt] = *(const bfrag*)(Bn + kt * 32);
    }
    f32x4 tmp[4];
#pragma unroll
    for (int m = 0; m < 4; ++m) tmp[m] = (f32x4){0.f, 0.f, 0.f, 0.f};
#pragma unroll
    for (int kt = 0; kt < 4; ++kt)
#pragma unroll
      for (int m = 0; m < 4; ++m)
        tmp[m] = __builtin_amdgcn_mfma_f32_16x16x32_bf16(a[m][kt], bc[kt], tmp[m], 0, 0, 0);
#pragma unroll
    for (int m = 0; m < 4; ++m) {
      f32x4 cf = *(const f32x4*)&coefT[n][m * 16 + quad * 4];
      out[m] += cf * tmp[m];
    }
    if (n + 1 < NOPS) {
#pragma unroll
      for (int kt = 0; kt < 4; ++kt) bc[kt] = bn[kt];
    }
  }
  __syncthreads();

  // ---- P3: AO -> xsb (bf16)
#pragma unroll
  for (int m = 0; m < 4; ++m)
#pragma unroll
    for (int r = 0; r < 4; ++r)
      xsb[m * 16 + quad * 4 + r][w * 16 + mrow] = f2b_bits(out[m][r]);
  __syncthreads();

  // ---- P4 (all 8 waves): mix GEMM + residual + mem term + LN
  // wave w: m-tile = w&3, column half = (w>>2)*64.
  const int mtile = w & 3;
  const int ch = (w >> 2) * 64;
  {
    bfrag a2[4];
#pragma unroll
    for (int kt = 0; kt < 4; ++kt)
      a2[kt] = *(const bfrag*)&xsb[mtile * 16 + mrow][kt * 32 + quad * 8];

    f32x4 acc[4];
#pragma unroll
    for (int i = 0; i < 4; ++i) acc[i] = (f32x4){0.f, 0.f, 0.f, 0.f};
#pragma unroll
    for (int kt = 0; kt < 4; ++kt)
#pragma unroll
      for (int nt = 0; nt < 4; ++nt) {
        bfrag b = *(const bfrag*)(WmixA + (size_t)(ch + nt * 16 + mrow) * DR + kt * 32 + quad * 8);
        acc[nt] = __builtin_amdgcn_mfma_f32_16x16x32_bf16(a2[kt], b, acc[nt], 0, 0, 0);
      }

    float v[4][4];
#pragma unroll
    for (int nt = 0; nt < 4; ++nt) {
      const int col = ch + nt * 16 + mrow;
#pragma unroll
      for (int r = 0; r < 4; ++r) {
        const int t = mtile * 16 + quad * 4 + r;
        float y0 = 0.f;
#pragma unroll
        for (int j = 0; j < 16; ++j) y0 += attn[t][j] * SBw[j * 128 + col];
        v[nt][r] = acc[nt][r] + xsf[t][col] + y0;
      }
    }
    float s[4], q[4];
#pragma unroll
    for (int r = 0; r < 4; ++r) {
      float ps = 0.f, pq = 0.f;
#pragma unroll
      for (int nt = 0; nt < 4; ++nt) { ps += v[nt][r]; pq += v[nt][r] * v[nt][r]; }
      s[r] = ps; q[r] = pq;
    }
#pragma unroll
    for (int m = 1; m < 16; m <<= 1)
#pragma unroll
      for (int r = 0; r < 4; ++r) {
        s[r] += __shfl_xor(s[r], m, 64);
        q[r] += __shfl_xor(q[r], m, 64);
      }
    if (mrow == 0)
#pragma unroll
      for (int r = 0; r < 4; ++r) { partS[w][quad][r] = s[r]; partQ[w][quad][r] = q[r]; }
    __syncthreads();

    float mu[4], rsd[4];
#pragma unroll
    for (int r = 0; r < 4; ++r) {
      float ts = s[r] + partS[w ^ 4][quad][r];
      float tq = q[r] + partQ[w ^ 4][quad][r];
      mu[r] = ts * (1.f / DR);
      float var = tq * (1.f / DR) - mu[r] * mu[r];
      rsd[r] = rsqrtf(var + 1e-5f);
    }
    if (!emit) {
#pragma unroll
      for (int nt = 0; nt < 4; ++nt) {
        const int col = ch + nt * 16 + mrow;
        const float g = gammaF[col], bb = betaF[col];
#pragma unroll
        for (int r = 0; r < 4; ++r) {
          const int t = mtile * 16 + quad * 4 + r;
          X[(size_t)(t0 + t) * DR + col] = (v[nt][r] - mu[r]) * rsd[r] * g + bb;
        }
      }
      return;
    }
#pragma unroll
    for (int nt = 0; nt < 4; ++nt) {
      const int col = ch + nt * 16 + mrow;
      const float g = gammaF[col], bb = betaF[col];
#pragma unroll
      for (int r = 0; r < 4; ++r) {
        const int t = mtile * 16 + quad * 4 + r;
        float val = (v[nt][r] - mu[r]) * rsd[r] * g + bb;
        xsf[t][col] = val;
        xsb[t][col] = f2b_bits(val);
      }
    }
  }
  __syncthreads();   // xsf/xsb now hold final reason

  // ================= fused write signal (pass 2 only) ======================
  for (int p = tid; p < 1024; p += 512) {
    int t = p >> 4, j = p & 15;
    float a = 0.f;
#pragma unroll 8
    for (int d = 0; d < DR; ++d) a += xsf[t][d] * Mws[d * 16 + j];
    at2[t][j] = a * 0.088388347648318447f;
  }
  __syncthreads();

  if (tid < 64) {
    float z = 0.f;
#pragma unroll 8
    for (int d = 0; d < DR; ++d) z += xsf[tid][d] * WwgF[d];
    gp[tid] = wscF[0] / (1.f + expf(-z));
    float m = -1e30f;
#pragma unroll
    for (int j = 0; j < 16; ++j) m = fmaxf(m, at2[tid][j]);
    float s = 0.f;
#pragma unroll
    for (int j = 0; j < 16; ++j) { float e = expf(at2[tid][j] - m); at2[tid][j] = e; s += e; }
    float inv = 1.f / s;
#pragma unroll
    for (int j = 0; j < 16; ++j) at2[tid][j] *= inv;
  }
  __syncthreads();

  // wv GEMM + combine -> RF (8 waves: same mtile/ch split)
  {
    bfrag a2[4];
#pragma unroll
    for (int kt = 0; kt < 4; ++kt)
      a2[kt] = *(const bfrag*)&xsb[mtile * 16 + mrow][kt * 32 + quad * 8];

    f32x4 acc[4];
#pragma unroll
    for (int i = 0; i < 4; ++i) acc[i] = (f32x4){0.f, 0.f, 0.f, 0.f};
#pragma unroll
    for (int kt = 0; kt < 4; ++kt)
#pragma unroll
      for (int nt = 0; nt < 4; ++nt) {
        bfrag b = *(const bfrag*)(WwvB + (size_t)(ch + nt * 16 + mrow) * DR + kt * 32 + quad * 8);
        acc[nt] = __builtin_amdgcn_mfma_f32_16x16x32_bf16(a2[kt], b, acc[nt], 0, 0, 0);
      }

    const float c01 = wscF[0] * 0.1f;
#pragma unroll
    for (int nt = 0; nt < 4; ++nt) {
      const int col = ch + nt * 16 + mrow;
#pragma unroll
      for (int r = 0; r < 4; ++r) {
        const int t = mtile * 16 + quad * 4 + r;
        float mo = 0.f;
#pragma unroll
        for (int j = 0; j < 16; ++j) mo += at2[t][j] * slotsF[j * DR + col];
        float val = xsf[t][col] + gp[t] * acc[nt][r] + c01 * mo;
        RF[(size_t)(t0 + t) * DR + col] = f2b_bits(val);
      }
    }
  }
}

// ---------- up projection + residual, LDS-staged coalesced epilogue --------
__global__ __launch_bounds__(256) void k_up(const ushort* __restrict__ Rf,
                                            const ushort* __restrict__ WuE,
                                            const float* __restrict__ hidden,
                                            float* __restrict__ out) {
  __shared__ float cs[64][132];

  const int wave = threadIdx.x >> 6, lane = threadIdx.x & 63;
  const int quad = lane >> 4, mrow = lane & 15;
  const int mt = blockIdx.x >> 3, ngrp = blockIdx.x & 7;
  const int m0b = mt * 64;
  const int m0 = m0b + wave * 16;
  const int c0 = ngrp * 128;

  f32x4 acc[8];
#pragma unroll
  for (int i = 0; i < 8; ++i) acc[i] = (f32x4){0.f, 0.f, 0.f, 0.f};

  const ushort* Ap = Rf + (size_t)(m0 + mrow) * DR + quad * 8;
#pragma unroll
  for (int kt = 0; kt < 4; ++kt) {
    bfrag a = *(const bfrag*)(Ap + kt * 32);
#pragma unroll
    for (int nt = 0; nt < 8; ++nt) {
      const ushort* Bp = WuE + (size_t)(c0 + nt * 16 + mrow) * DR + kt * 32 + quad * 8;
      bfrag b = *(const bfrag*)Bp;
      acc[nt] = __builtin_amdgcn_mfma_f32_16x16x32_bf16(a, b, acc[nt], 0, 0, 0);
    }
  }
#pragma unroll
  for (int nt = 0; nt < 8; ++nt)
#pragma unroll
    for (int r = 0; r < 4; ++r)
      cs[wave * 16 + quad * 4 + r][nt * 16 + mrow] = acc[nt][r];
  __syncthreads();

#pragma unroll
  for (int k = 0; k < 8; ++k) {
    const int i = threadIdx.x + k * 256;
    const int t = i >> 5, c4 = (i & 31) * 4;
    const size_t idx = (size_t)(m0b + t) * DM + c0 + c4;
    float4 h = *(const float4*)(hidden + idx);
    float4 v;
    v.x = h.x + cs[t][c4];
    v.y = h.y + cs[t][c4 + 1];
    v.z = h.z + cs[t][c4 + 2];
    v.w = h.w + cs[t][c4 + 3];
    *(float4*)(out + idx) = v;
  }
}

// ---------------------------------------------------------------------------
extern "C" void kernel_launch(void* const* d_in, const int* in_sizes, int n_in,
                              void* d_out, int out_size, void* d_ws, size_t ws_size,
                              hipStream_t stream) {
  int ns[20]; int nn = 0; int lastsc = -1;
  for (int i = 0; i < n_in; ++i) {
    if (in_sizes[i] == 1) lastsc = i;
    else if (nn < 20) ns[nn++] = i;
  }
  int iH = 0, iWd = 2, iWu = 3, iOps = 4, iWr = 5, iSl = 6, iRe = 7,
      iWk = 8, iWg = 9, iWv = 10, iMx = 11, iG = 12, iB = 13;
  if (nn >= 13) {
    iH  = ns[0];  iWd = ns[1];  iWu = ns[2];  iOps = ns[3]; iWr = ns[4];
    iSl = ns[5];  iRe = ns[6];  iWk = ns[7];  iWg = ns[8];  iWv = ns[9];
    iMx = ns[10]; iG  = ns[11]; iB  = ns[12];
  }
  const float* hidden   = (const float*)d_in[iH];
  const float* W_down   = (const float*)d_in[iWd];
  const float* W_up     = (const float*)d_in[iWu];
  const float* opsw     = (const float*)d_in[iOps];
  const float* W_router = (const float*)d_in[iWr];
  const float* slots    = (const float*)d_in[iSl];
  const float* W_read   = (const float*)d_in[iRe];
  const float* W_wk     = (const float*)d_in[iWk];
  const float* W_wg     = (const float*)d_in[iWg];
  const float* W_wv     = (const float*)d_in[iWv];
  const float* W_mix    = (const float*)d_in[iMx];
  const float* lng      = (const float*)d_in[iG];
  const float* lnb      = (const float*)d_in[iB];
  const float* wscale   = (lastsc >= 0) ? (const float*)d_in[lastsc] : (const float*)d_in[iG];
  const int has_wsc     = (lastsc >= 0) ? 1 : 0;

  char* ws = (char*)d_ws;
  float*  sums   = (float*)(ws + OFF_SUMS);
  float*  opsSc  = (float*)(ws + OFF_OPSSC);
  ushort* WdE    = (ushort*)(ws + OFF_WDE);
  ushort* WuE    = (ushort*)(ws + OFF_WUE);
  float*  WrT    = (float*)(ws + OFF_WRT);
  ushort* opsB   = (ushort*)(ws + OFF_OPSB);
  ushort* WmixA  = (ushort*)(ws + OFF_WMIXA);
  ushort* WwvB   = (ushort*)(ws + OFF_WWVB);
  float*  Mrs    = (float*)(ws + OFF_MRS);
  float*  Mws    = (float*)(ws + OFF_MWS);
  float*  SBw    = (float*)(ws + OFF_SB);
  float*  slotsF = (float*)(ws + OFF_SLOTS);
  float*  WwgF   = (float*)(ws + OFF_WWG);
  float*  gammaF = (float*)(ws + OFF_GAMMA);
  float*  betaF  = (float*)(ws + OFF_BETA);
  float*  wscF   = (float*)(ws + OFF_WSC);
  ushort* RF     = (ushort*)(ws + OFF_RF);

  float* X = (float*)d_out;

  hipMemsetAsync(ws + OFF_SUMS, 0, 256, stream);
  k_absum_all<<<dim3(8, 35), 256, 0, stream>>>(W_down, W_router, W_up, opsw, sums);
  k_build<<<3250, 256, 0, stream>>>(W_down, W_up, W_router, opsw, W_read, W_wk, W_wg,
                                    W_wv, W_mix, slots, lng, lnb, wscale, has_wsc,
                                    sums, WdE, WuE, WrT, opsB, opsSc, WmixA, WwvB,
                                    Mrs, Mws, SBw, slotsF, WwgF, gammaF, betaF, wscF);
  k_down<<<1024, 256, 0, stream>>>(hidden, WdE, X);
  k_pass2<<<256, 512, 0, stream>>>(X, RF, 0, WrT, opsB, opsSc, WmixA, Mrs, SBw,
                                   gammaF, betaF, WwvB, Mws, slotsF, WwgF, wscF);
  k_pass2<<<256, 512, 0, stream>>>(X, RF, 1, WrT, opsB, opsSc, WmixA, Mrs, SBw,
                                   gammaF, betaF, WwvB, Mws, slotsF, WwgF, wscF);
  k_up<<<2048, 256, 0, stream>>>(RF, WuE, hidden, X);
}